// Round 3
// baseline (693.986 us; speedup 1.0000x reference)
//
#include <hip/hip_runtime.h>
#include <math.h>

// CropRoi — R2 PROBE build: identical algorithm to R1, but the single dispatch
// repeats the full computation REPS times with a per-rep channel rotation so
// (a) the dispatch exceeds rocprof's top-5 threshold and returns counters,
// (b) kernel time = (dur_total - R1 dur_total)/(REPS-1),
// (c) output is bit-identical (every rep writes every output, same values).
//
// f:         (B=2, C=128, 32, 64, 64) float32
// proposals: (N=32, 8) float32 = [b, score, cz, cy, cx, sz, sy, sx]
// out:       (N=32, C=128, 7, 7, 7) float32

constexpr int C_CH = 128;
constexpr int FD = 32, FH = 64, FW = 64;
constexpr int CH_VOL = FD * FH * FW;        // 131072
constexpr int LMAX = 17;                    // max crop extent: 64/4 + 1
constexpr int VOL = LMAX * LMAX * LMAX;     // 4913
constexpr int CPB = 2;                      // channels per block
constexpr int THREADS = 256;
constexpr int REPS = 16;                    // probe multiplier

__global__ __launch_bounds__(THREADS) void crop_roi_kernel(
    const float* __restrict__ f,
    const float* __restrict__ proposals,
    float* __restrict__ out)
{
    __shared__ float lds[CPB * VOL];        // 39316 B

    const int n    = blockIdx.x;            // proposal
    const int c0ch = blockIdx.y * CPB;      // base channel-pair of this block

    const float* p = proposals + n * 8;
    const int   b  = (int)p[0];
    const float cz = p[2], cy = p[3], cx = p[4];
    const float sz = p[5], sy = p[6], sx = p[7];

    const int c0z = max((int)floorf((cz - sz * 0.5f) * 0.25f), 0);
    const int c0y = max((int)floorf((cy - sy * 0.5f) * 0.25f), 0);
    const int c0x = max((int)floorf((cx - sx * 0.5f) * 0.25f), 0);
    const int c1z = min((int)ceilf((cz + sz * 0.5f) * 0.25f), FD);
    const int c1y = min((int)ceilf((cy + sy * 0.5f) * 0.25f), FH);
    const int c1x = min((int)ceilf((cx + sx * 0.5f) * 0.25f), FW);
    const int Lz = c1z - c0z, Ly = c1y - c0y, Lx = c1x - c0x;

    for (int rep = 0; rep < REPS; ++rep) {
        // rotate channel assignment per rep: full coverage every rep,
        // distinct addresses across reps (defeats CSE), identical final output.
        const int ce = (c0ch + rep * CPB) & (C_CH - 1);

        // ---- stage clamped 17^3 crop per channel into LDS
        const float* fb = f + (size_t)(b * C_CH + ce) * CH_VOL
                            + c0z * (FH * FW) + c0y * FW + c0x;
        #pragma unroll 4
        for (int e = threadIdx.x; e < CPB * VOL; e += THREADS) {
            int cl = e / VOL;
            int r  = e % VOL;
            int z  = r / (LMAX * LMAX);
            int y  = (r / LMAX) % LMAX;
            int x  = r % LMAX;
            int zc = min(z, Lz - 1);
            int yc = min(y, Ly - 1);
            int xc = min(x, Lx - 1);
            lds[e] = fb[(size_t)cl * CH_VOL + zc * (FH * FW) + yc * FW + xc];
        }
        __syncthreads();

        // ---- pool 7x7x7 per channel from LDS
        for (int o = threadIdx.x; o < CPB * 343; o += THREADS) {
            int cl = o / 343;
            int r  = o % 343;
            int iz = r / 49, iy = (r / 7) % 7, ix = r % 7;

            int zs = (iz * Lz) / 7, ze = ((iz + 1) * Lz + 6) / 7;
            int ys = (iy * Ly) / 7, ye = ((iy + 1) * Ly + 6) / 7;
            int xs = (ix * Lx) / 7, xe = ((ix + 1) * Lx + 6) / 7;

            const float* Lp = lds + cl * VOL;
            float m = -INFINITY;
            for (int z = zs; z < ze; ++z) {
                for (int y = ys; y < ye; ++y) {
                    int base = z * (LMAX * LMAX) + y * LMAX;
                    int xm = xe - 1;
                    float v0 = Lp[base + xs];
                    float v1 = Lp[base + min(xs + 1, xm)];
                    float v2 = Lp[base + min(xs + 2, xm)];
                    float v3 = Lp[base + min(xs + 3, xm)];
                    m = fmaxf(m, fmaxf(fmaxf(v0, v1), fmaxf(v2, v3)));
                }
            }
            out[(size_t)(n * C_CH + ce) * 343 + o] = m;
        }
        __syncthreads();   // protect LDS before next rep restages
    }
}

extern "C" void kernel_launch(void* const* d_in, const int* in_sizes, int n_in,
                              void* d_out, int out_size, void* d_ws, size_t ws_size,
                              hipStream_t stream) {
    const float* f         = (const float*)d_in[0];
    // d_in[1] = `inputs` zeros tensor — shape-only in the reference; unused.
    const float* proposals = (const float*)d_in[2];
    float* out             = (float*)d_out;

    dim3 grid(32, C_CH / CPB);   // 32 proposals x 64 channel-pairs = 2048 blocks
    crop_roi_kernel<<<grid, THREADS, 0, stream>>>(f, proposals, out);
}

// Round 4
// 257.118 us; speedup vs baseline: 2.6991x; 2.6991x over previous
//
#include <hip/hip_runtime.h>
#include <math.h>

// CropRoi — R3: exact-region LDS staging (division-free), window-bound table,
// 2 channels per block sharing window math.
//
// f:         (B=2, C=128, 32, 64, 64) float32
// proposals: (N=32, 8) float32 = [b, score, cz, cy, cx, sz, sy, sx]
// out:       (N=32, C=128, 7, 7, 7) float32
//
// Reference semantics:
//   c0 = max(floor((center - side/2)/4), 0); c1 = min(ceil((center + side/2)/4), dim)
//   L = c1 - c0   (here always in [4,17]: sides >= 16, boxes interior)
//   window i = [i*L//7, ceil((i+1)*L/7))  relative to c0; width in [1,4].

constexpr int C_CH = 128;
constexpr int FD = 32, FH = 64, FW = 64;
constexpr int CH_VOL = FD * FH * FW;        // 131072
constexpr int LMAX = 17;                    // max crop extent: 64/4 + 1
constexpr int VOL = LMAX * LMAX * LMAX;     // 4913
constexpr int CPB = 2;                      // channels per block
constexpr int THREADS = 256;

__global__ __launch_bounds__(THREADS) void crop_roi_kernel(
    const float* __restrict__ f,
    const float* __restrict__ proposals,
    float* __restrict__ out)
{
    __shared__ float lds[CPB * VOL];        // 39316 B
    __shared__ int ws_[3][7], we_[3][7];    // pooling window bounds per dim

    const int n    = blockIdx.x;            // proposal
    const int c0ch = blockIdx.y * CPB;      // first channel of this block

    const float* p = proposals + n * 8;
    const int   b  = (int)p[0];
    const float cz = p[2], cy = p[3], cx = p[4];
    const float sz = p[5], sy = p[6], sx = p[7];

    const int c0z = max((int)floorf((cz - sz * 0.5f) * 0.25f), 0);
    const int c0y = max((int)floorf((cy - sy * 0.5f) * 0.25f), 0);
    const int c0x = max((int)floorf((cx - sx * 0.5f) * 0.25f), 0);
    const int c1z = min((int)ceilf((cz + sz * 0.5f) * 0.25f), FD);
    const int c1y = min((int)ceilf((cy + sy * 0.5f) * 0.25f), FH);
    const int c1x = min((int)ceilf((cx + sx * 0.5f) * 0.25f), FW);
    const int Lz = c1z - c0z, Ly = c1y - c0y, Lx = c1x - c0x;

    // ---- window-bound table: 21 threads compute, everyone reads from LDS
    if (threadIdx.x < 21) {
        const int d = threadIdx.x / 7;      // 0=z, 1=y, 2=x
        const int i = threadIdx.x % 7;
        const int L = (d == 0) ? Lz : (d == 1) ? Ly : Lx;
        ws_[d][i] = (i * L) / 7;
        we_[d][i] = ((i + 1) * L + 6) / 7;
    }

    // ---- exact-region staging: only the real crop, incremental addressing
    const int tx = threadIdx.x & 31;        // x lane (Lx <= 17 < 32: one shot)
    const int ty = threadIdx.x >> 5;        // y strider, 0..7
    const float* fb = f + (size_t)(b * C_CH + c0ch) * CH_VOL
                        + c0z * (FH * FW) + c0y * FW + c0x;
    for (int cl = 0; cl < CPB; ++cl) {
        const float* fc = fb + (size_t)cl * CH_VOL;
        float* Lc = lds + cl * VOL;
        if (tx < Lx) {
            for (int z = 0; z < Lz; ++z) {
                const float* fz = fc + z * (FH * FW);
                float* Lzp = Lc + z * (LMAX * LMAX);
                for (int y = ty; y < Ly; y += 8) {
                    Lzp[y * LMAX + tx] = fz[y * FW + tx];
                }
            }
        }
    }
    __syncthreads();

    // ---- pooling: one (iz,iy,ix) per r-iteration, both channels together
    for (int r = threadIdx.x; r < 343; r += THREADS) {
        const int iz = r / 49, iy = (r / 7) % 7, ix = r % 7;
        const int zs = ws_[0][iz], ze = we_[0][iz];
        const int ys = ws_[1][iy], ye = we_[1][iy];
        const int xs = ws_[2][ix], xm = we_[2][ix] - 1;
        const int x1 = min(xs + 1, xm);     // clamped 4-wide x window
        const int x2 = min(xs + 2, xm);     // (duplicates harmless under max)
        const int x3 = min(xs + 3, xm);

        float m0 = -INFINITY, m1 = -INFINITY;
        for (int z = zs; z < ze; ++z) {
            for (int y = ys; y < ye; ++y) {
                const int base = z * (LMAX * LMAX) + y * LMAX;
                const float* L0 = lds + base;
                const float* L1 = lds + VOL + base;
                m0 = fmaxf(m0, fmaxf(fmaxf(L0[xs], L0[x1]), fmaxf(L0[x2], L0[x3])));
                m1 = fmaxf(m1, fmaxf(fmaxf(L1[xs], L1[x1]), fmaxf(L1[x2], L1[x3])));
            }
        }
        const size_t ob = (size_t)(n * C_CH + c0ch) * 343 + r;
        out[ob]       = m0;
        out[ob + 343] = m1;
    }
}

extern "C" void kernel_launch(void* const* d_in, const int* in_sizes, int n_in,
                              void* d_out, int out_size, void* d_ws, size_t ws_size,
                              hipStream_t stream) {
    const float* f         = (const float*)d_in[0];
    // d_in[1] = `inputs` zeros tensor — shape-only in the reference; unused.
    const float* proposals = (const float*)d_in[2];
    float* out             = (float*)d_out;

    dim3 grid(32, C_CH / CPB);   // 32 proposals x 64 channel-pairs = 2048 blocks
    crop_roi_kernel<<<grid, THREADS, 0, stream>>>(f, proposals, out);
}

// Round 5
// 213.315 us; speedup vs baseline: 3.2533x; 1.2053x over previous
//
#include <hip/hip_runtime.h>
#include <math.h>

// CropRoi — R4: grid-stride staging (full-wave MLP, R1-style) over an
// exact-z / clamped-yx region (Lz x 17 x 17), compile-time divisors only;
// CPB=1 for 8 blocks/CU occupancy; LDS window-bound table for pooling.
//
// f:         (B=2, C=128, 32, 64, 64) float32
// proposals: (N=32, 8) float32 = [b, score, cz, cy, cx, sz, sy, sx]
// out:       (N=32, C=128, 7, 7, 7) float32
//
// Reference semantics:
//   c0 = max(floor((center - side/2)/4), 0); c1 = min(ceil((center + side/2)/4), dim)
//   L = c1 - c0   (always in [4,17] here)
//   window i = [i*L//7, ceil((i+1)*L/7)) relative to c0; width in [1,4].
//
// Staged cells with y>=Ly or x>=Lx are clamped duplicates; pooling windows
// never index them (window bounds < L), they only keep index math division-free.

constexpr int C_CH = 128;
constexpr int FD = 32, FH = 64, FW = 64;
constexpr int CH_VOL = FD * FH * FW;        // 131072
constexpr int LMAX = 17;                    // max crop extent: 64/4 + 1
constexpr int VOL = LMAX * LMAX * LMAX;     // 4913 floats (19.7 KB)
constexpr int THREADS = 256;

__global__ __launch_bounds__(THREADS) void crop_roi_kernel(
    const float* __restrict__ f,
    const float* __restrict__ proposals,
    float* __restrict__ out)
{
    __shared__ float lds[VOL];
    __shared__ int ws_[3][7], we_[3][7];

    const int n = blockIdx.x;               // proposal
    const int c = blockIdx.y;               // channel

    const float* p = proposals + n * 8;
    const int   b  = (int)p[0];
    const float cz = p[2], cy = p[3], cx = p[4];
    const float sz = p[5], sy = p[6], sx = p[7];

    const int c0z = max((int)floorf((cz - sz * 0.5f) * 0.25f), 0);
    const int c0y = max((int)floorf((cy - sy * 0.5f) * 0.25f), 0);
    const int c0x = max((int)floorf((cx - sx * 0.5f) * 0.25f), 0);
    const int c1z = min((int)ceilf((cz + sz * 0.5f) * 0.25f), FD);
    const int c1y = min((int)ceilf((cy + sy * 0.5f) * 0.25f), FH);
    const int c1x = min((int)ceilf((cx + sx * 0.5f) * 0.25f), FW);
    const int Lz = c1z - c0z, Ly = c1y - c0y, Lx = c1x - c0x;

    // window-bound table: 21 threads compute, all read via LDS
    if (threadIdx.x < 21) {
        const int d = threadIdx.x / 7;      // 0=z, 1=y, 2=x
        const int i = threadIdx.x % 7;
        const int L = (d == 0) ? Lz : (d == 1) ? Ly : Lx;
        ws_[d][i] = (i * L) / 7;
        we_[d][i] = ((i + 1) * L + 6) / 7;
    }

    // ---- staging: Lz x 17 x 17, grid-stride, all lanes active, high MLP
    const float* fc = f + (size_t)(b * C_CH + c) * CH_VOL
                        + c0z * (FH * FW) + c0y * FW + c0x;
    const int Lym1 = Ly - 1, Lxm1 = Lx - 1;
    const int tot = Lz * (LMAX * LMAX);
    #pragma unroll 4
    for (int e = threadIdx.x; e < tot; e += THREADS) {
        int z = e / (LMAX * LMAX);          // compile-time magic mul
        int r = e - z * (LMAX * LMAX);
        int y = r / LMAX;                   // compile-time magic mul
        int x = r - y * LMAX;
        lds[e] = fc[z * (FH * FW) + min(y, Lym1) * FW + min(x, Lxm1)];
    }
    __syncthreads();

    // ---- pooling: 343 outputs, contiguous write
    for (int r = threadIdx.x; r < 343; r += THREADS) {
        const int iz = r / 49, iy = (r / 7) % 7, ix = r % 7;
        const int zs = ws_[0][iz], ze = we_[0][iz];
        const int ys = ws_[1][iy], ye = we_[1][iy];
        const int xs = ws_[2][ix], xm = we_[2][ix] - 1;
        const int x1 = min(xs + 1, xm);     // clamped 4-wide x window
        const int x2 = min(xs + 2, xm);     // (duplicates harmless under max)
        const int x3 = min(xs + 3, xm);

        float m = -INFINITY;
        for (int z = zs; z < ze; ++z) {
            for (int y = ys; y < ye; ++y) {
                const float* Lp = lds + z * (LMAX * LMAX) + y * LMAX;
                m = fmaxf(m, fmaxf(fmaxf(Lp[xs], Lp[x1]), fmaxf(Lp[x2], Lp[x3])));
            }
        }
        out[(size_t)(n * C_CH + c) * 343 + r] = m;
    }
}

extern "C" void kernel_launch(void* const* d_in, const int* in_sizes, int n_in,
                              void* d_out, int out_size, void* d_ws, size_t ws_size,
                              hipStream_t stream) {
    const float* f         = (const float*)d_in[0];
    // d_in[1] = `inputs` zeros tensor — shape-only in the reference; unused.
    const float* proposals = (const float*)d_in[2];
    float* out             = (float*)d_out;

    dim3 grid(32, C_CH);     // 32 proposals x 128 channels = 4096 blocks
    crop_roi_kernel<<<grid, THREADS, 0, stream>>>(f, proposals, out);
}

// Round 6
// 211.729 us; speedup vs baseline: 3.2777x; 1.0075x over previous
//
#include <hip/hip_runtime.h>
#include <math.h>

// CropRoi — R5: float4-vectorized staging. Each crop row is staged as aligned
// 16B chunks from ax0 = c0x & ~3; LDS layout [z][y][20] makes the LDS write
// address exactly 16*v bytes (lane-linear, zero index math on the write).
// Rows y>=Ly / planes z>=Lz are skipped entirely: pooling window bounds are
// strictly < L per dim, so those cells are never read.
//
// f:         (B=2, C=128, 32, 64, 64) float32
// proposals: (N=32, 8) float32 = [b, score, cz, cy, cx, sz, sy, sx]
// out:       (N=32, C=128, 7, 7, 7) float32
//
// Reference semantics:
//   c0 = max(floor((center - side/2)/4), 0); c1 = min(ceil((center + side/2)/4), dim)
//   L = c1 - c0  (in [4,17] here); window i = [i*L//7, ceil((i+1)*L/7)), width 1..4.

constexpr int C_CH = 128;
constexpr int FD = 32, FH = 64, FW = 64;
constexpr int CH_VOL = FD * FH * FW;        // 131072
constexpr int LMAX = 17;                    // max crop extent per dim
constexpr int XPAD = 20;                    // row floats: 17 + up to 3 align shift
constexpr int VQ   = XPAD / 4;              // 5 float4 per row
constexpr int PLQ  = LMAX * VQ;             // 85 float4 per z-plane
constexpr int THREADS = 256;

__global__ __launch_bounds__(THREADS) void crop_roi_kernel(
    const float* __restrict__ f,
    const float* __restrict__ proposals,
    float* __restrict__ out)
{
    __shared__ __align__(16) float lds[LMAX * LMAX * XPAD];   // 23120 B
    __shared__ int ws_[3][7], we_[3][7];

    const int n = blockIdx.x;               // proposal
    const int c = blockIdx.y;               // channel

    const float* p = proposals + n * 8;
    const int   b  = (int)p[0];
    const float cz = p[2], cy = p[3], cx = p[4];
    const float sz = p[5], sy = p[6], sx = p[7];

    const int c0z = max((int)floorf((cz - sz * 0.5f) * 0.25f), 0);
    const int c0y = max((int)floorf((cy - sy * 0.5f) * 0.25f), 0);
    const int c0x = max((int)floorf((cx - sx * 0.5f) * 0.25f), 0);
    const int c1z = min((int)ceilf((cz + sz * 0.5f) * 0.25f), FD);
    const int c1y = min((int)ceilf((cy + sy * 0.5f) * 0.25f), FH);
    const int c1x = min((int)ceilf((cx + sx * 0.5f) * 0.25f), FW);
    const int Lz = c1z - c0z, Ly = c1y - c0y, Lx = c1x - c0x;

    // window-bound table: 21 threads compute, all read via LDS
    if (threadIdx.x < 21) {
        const int d = threadIdx.x / 7;      // 0=z, 1=y, 2=x
        const int i = threadIdx.x % 7;
        const int L = (d == 0) ? Lz : (d == 1) ? Ly : Lx;
        ws_[d][i] = (i * L) / 7;
        we_[d][i] = ((i + 1) * L + 6) / 7;
    }

    // ---- vectorized staging ----
    // aligned x start; end = align_up(c0x+Lx,4) <= 64 (since c0x+Lx <= 64): safe.
    const int ax0   = c0x & ~3;
    const int shift = c0x - ax0;                  // 0..3
    const int nvec  = (shift + Lx + 3) >> 2;      // float4 chunks per row, <= 5

    // 16B-aligned float4 base: all offset terms are multiples of 4 floats.
    const float4* f4 = reinterpret_cast<const float4*>(
        f + (size_t)(b * C_CH + c) * CH_VOL + c0z * (FH * FW) + c0y * FW + ax0);
    float4* lds4 = reinterpret_cast<float4*>(lds);

    const int tot = Lz * PLQ;               // <= 1445 float4 slots
    for (int v = threadIdx.x; v < tot; v += THREADS) {
        const int z = v / PLQ;              // compile-time magic mul
        const int r = v - z * PLQ;
        const int y = r / VQ;               // compile-time magic mul
        const int q = r - y * VQ;
        if (y < Ly && q < nvec) {
            // global float4 index: z*(FH*FW/4) + y*(FW/4) + q
            lds4[v] = f4[z * (FH * FW / 4) + y * (FW / 4) + q];
        }
    }
    __syncthreads();

    // ---- pooling: 343 outputs, contiguous write ----
    for (int r = threadIdx.x; r < 343; r += THREADS) {
        const int iz = r / 49, iy = (r / 7) % 7, ix = r % 7;
        const int zs = ws_[0][iz], ze = we_[0][iz];
        const int ys = ws_[1][iy], ye = we_[1][iy];
        const int xs = ws_[2][ix] + shift, xm = we_[2][ix] - 1 + shift;
        const int x1 = min(xs + 1, xm);     // clamped 4-wide x window
        const int x2 = min(xs + 2, xm);     // (duplicates harmless under max)
        const int x3 = min(xs + 3, xm);

        float m = -INFINITY;
        for (int z = zs; z < ze; ++z) {
            for (int y = ys; y < ye; ++y) {
                const float* Lp = lds + (z * LMAX + y) * XPAD;
                m = fmaxf(m, fmaxf(fmaxf(Lp[xs], Lp[x1]), fmaxf(Lp[x2], Lp[x3])));
            }
        }
        out[(size_t)(n * C_CH + c) * 343 + r] = m;
    }
}

extern "C" void kernel_launch(void* const* d_in, const int* in_sizes, int n_in,
                              void* d_out, int out_size, void* d_ws, size_t ws_size,
                              hipStream_t stream) {
    const float* f         = (const float*)d_in[0];
    // d_in[1] = `inputs` zeros tensor — shape-only in the reference; unused.
    const float* proposals = (const float*)d_in[2];
    float* out             = (float*)d_out;

    dim3 grid(32, C_CH);     // 32 proposals x 128 channels = 4096 blocks
    crop_roi_kernel<<<grid, THREADS, 0, stream>>>(f, proposals, out);
}